// Round 6
// baseline (2478.879 us; speedup 1.0000x reference)
//
#include <hip/hip_runtime.h>
#include <hip/hip_bf16.h>
#include <math.h>

#define S_LEN 2048
#define NHEAD 16
#define DMODEL 1024

__device__ __forceinline__ int mask_at(const void* mp, int enc, int s) {
    if (enc) return ((const unsigned char*)mp)[s] != 0;
    return ((const unsigned int*)mp)[s] != 0u;
}

// flags[0]: 1 if mask is byte-encoded bools, 0 if word-encoded (int32/float32)
__global__ void detect_kernel(const void* __restrict__ mask, int* __restrict__ flags) {
    if (threadIdx.x == 0 && blockIdx.x == 0) {
        const unsigned int* m = (const unsigned int*)mask;
        int bytey = 0;
        for (int i = 0; i < 8; ++i) {
            unsigned int u = m[i];
            if (u != 0u && u != 1u && u != 0x3F800000u) bytey = 1;
        }
        flags[0] = bytey;
    }
}

// x-projection (+optional fused b_rotate GEMM & RoPE). Writes fp32 [h][s][d].
// woff: element offset of weight matrix inside ll. dorope: 1 -> rope(x)*b_rotate path.
__global__ __launch_bounds__(256)
void proj_kernel(const float* __restrict__ X, const float* __restrict__ b_emb,
                 const float* __restrict__ ll, const float* __restrict__ bproj,
                 float* __restrict__ outf, int woff, int dorope) {
    __shared__ float Ax[16][68], Ab[16][68], Wx[16][68], Wb[16][68];
    const int t = threadIdx.x;
    const int head = blockIdx.x;
    const int s0 = blockIdx.y * 64;
    const int tx = t & 15, ty = t >> 4;
    const int arow = t >> 2, akg = (t & 3) * 4;
    const int wrow = t >> 4, wng = (t & 15) * 4;

    float acc[4][4] = {}, accb[4][4] = {};
    for (int k0 = 0; k0 < DMODEL; k0 += 16) {
        float4 av = *(const float4*)&X[(s0 + arow) * DMODEL + k0 + akg];
        float4 wv = *(const float4*)&ll[woff + (k0 + wrow) * DMODEL + head * 64 + wng];
        Ax[akg + 0][arow] = av.x; Ax[akg + 1][arow] = av.y;
        Ax[akg + 2][arow] = av.z; Ax[akg + 3][arow] = av.w;
        *(float4*)&Wx[wrow][wng] = wv;
        if (dorope) {
            float4 bv = *(const float4*)&b_emb[(s0 + arow) * DMODEL + k0 + akg];
            float4 pv = *(const float4*)&bproj[(k0 + wrow) * DMODEL + head * 64 + wng];
            Ab[akg + 0][arow] = bv.x; Ab[akg + 1][arow] = bv.y;
            Ab[akg + 2][arow] = bv.z; Ab[akg + 3][arow] = bv.w;
            *(float4*)&Wb[wrow][wng] = pv;
        }
        __syncthreads();
#pragma unroll
        for (int kk = 0; kk < 16; ++kk) {
            float4 a = *(float4*)&Ax[kk][ty * 4];
            float4 wa = *(float4*)&Wx[kk][tx * 4];
            float af[4] = {a.x, a.y, a.z, a.w};
            float wf[4] = {wa.x, wa.y, wa.z, wa.w};
#pragma unroll
            for (int i = 0; i < 4; ++i)
#pragma unroll
                for (int j = 0; j < 4; ++j) acc[i][j] += af[i] * wf[j];
            if (dorope) {
                float4 b = *(float4*)&Ab[kk][ty * 4];
                float4 wb = *(float4*)&Wb[kk][tx * 4];
                float bf[4] = {b.x, b.y, b.z, b.w};
                float pf[4] = {wb.x, wb.y, wb.z, wb.w};
#pragma unroll
                for (int i = 0; i < 4; ++i)
#pragma unroll
                    for (int j = 0; j < 4; ++j) accb[i][j] += bf[i] * pf[j];
            }
        }
        __syncthreads();
    }

    if (dorope) {
        // RoPE pairs p0=2tx (dims 4tx,4tx+1), p1=2tx+1 (dims 4tx+2,4tx+3)
        double inv0 = pow(10000.0, -(double)(2 * tx) / 32.0);
        double inv1 = pow(10000.0, -(double)(2 * tx + 1) / 32.0);
#pragma unroll
        for (int i = 0; i < 4; ++i) {
            int sr = s0 + ty * 4 + i;
            double a0 = (double)sr * inv0, a1 = (double)sr * inv1;
            float sn0 = (float)sin(a0), cs0 = (float)cos(a0);
            float sn1 = (float)sin(a1), cs1 = (float)cos(a1);
            float e0 = acc[i][0] * cs0 - acc[i][1] * sn0;
            float o0 = acc[i][0] * sn0 + acc[i][1] * cs0;
            float e1 = acc[i][2] * cs1 - acc[i][3] * sn1;
            float o1 = acc[i][2] * sn1 + acc[i][3] * cs1;
            int base = (head * S_LEN + sr) * 64 + tx * 4;
            *(float4*)&outf[base] = make_float4(e0 * accb[i][0], o0 * accb[i][1],
                                                e1 * accb[i][2], o1 * accb[i][3]);
        }
    } else {
#pragma unroll
        for (int i = 0; i < 4; ++i) {
            int sr = s0 + ty * 4 + i;
            *(float4*)&outf[(head * S_LEN + sr) * 64 + tx * 4] =
                make_float4(acc[i][0], acc[i][1], acc[i][2], acc[i][3]);
        }
    }
}

// Flash attention over fp32 qr/kr/vr [h][s][d]. out FP32 [s][h*64+d].
__global__ __launch_bounds__(256)
void attn_kernel(const float* __restrict__ qr, const float* __restrict__ kr,
                 const float* __restrict__ vr, const void* __restrict__ mask,
                 float* __restrict__ out, const int* __restrict__ flags) {
    __shared__ float q_s[64][68];
    __shared__ float k_s[64][68];
    __shared__ float v_s[64][68];
    __shared__ float s_s[64][68];
    __shared__ float red_max[64][4];
    __shared__ float red_sum[64][4];
    __shared__ float row_m[64], row_l[64], row_alpha[64];
    __shared__ int mq_s[64], mk_s[64];

    const int menc = flags[0];
    const int t = threadIdx.x;
    const int h = blockIdx.y;
    const int s0 = blockIdx.x * 64;
    const int rg4 = (t >> 4) * 4;
    const int dg4 = (t & 15) * 4;
    const int rr = t >> 2;
    const int q4 = t & 3;

    if (t < 64) {
        row_m[t] = -INFINITY;
        row_l[t] = 0.0f;
        row_alpha[t] = 0.0f;
        mq_s[t] = mask_at(mask, menc, s0 + t);
    }
    const float* qbase = qr + (h * S_LEN + s0) * 64;
#pragma unroll
    for (int it = 0; it < 4; ++it) {
        int id = it * 256 + t;
        int row = id >> 4, c4 = (id & 15) * 4;
        *(float4*)&q_s[row][c4] = *(const float4*)&qbase[row * 64 + c4];
    }
    float o[4][4] = {};
    __syncthreads();

    const float* kb_h = kr + h * S_LEN * 64;
    const float* vb_h = vr + h * S_LEN * 64;

    for (int kt = 0; kt < 32; ++kt) {
        const int kb = kt * 64;
#pragma unroll
        for (int it = 0; it < 4; ++it) {
            int id = it * 256 + t;
            int row = id >> 4, c4 = (id & 15) * 4;
            *(float4*)&k_s[row][c4] = *(const float4*)&kb_h[(kb + row) * 64 + c4];
            *(float4*)&v_s[row][c4] = *(const float4*)&vb_h[(kb + row) * 64 + c4];
        }
        if (t < 64) mk_s[t] = mask_at(mask, menc, kb + t);
        __syncthreads();

        float sc[4][4] = {};
        for (int d0 = 0; d0 < 64; d0 += 4) {
            float qa[4][4], kbm[4][4];
#pragma unroll
            for (int i = 0; i < 4; ++i) {
                float4 a = *(float4*)&q_s[rg4 + i][d0];
                qa[i][0] = a.x; qa[i][1] = a.y; qa[i][2] = a.z; qa[i][3] = a.w;
            }
#pragma unroll
            for (int j = 0; j < 4; ++j) {
                float4 b = *(float4*)&k_s[dg4 + j][d0];
                kbm[j][0] = b.x; kbm[j][1] = b.y; kbm[j][2] = b.z; kbm[j][3] = b.w;
            }
#pragma unroll
            for (int i = 0; i < 4; ++i)
#pragma unroll
                for (int j = 0; j < 4; ++j)
#pragma unroll
                    for (int d = 0; d < 4; ++d) sc[i][j] += qa[i][d] * kbm[j][d];
        }
#pragma unroll
        for (int i = 0; i < 4; ++i) {
            bool mq = (mq_s[rg4 + i] != 0);
            float4 sv;
            sv.x = (mq && mk_s[dg4 + 0]) ? sc[i][0] * 0.125f : -1e30f;
            sv.y = (mq && mk_s[dg4 + 1]) ? sc[i][1] * 0.125f : -1e30f;
            sv.z = (mq && mk_s[dg4 + 2]) ? sc[i][2] * 0.125f : -1e30f;
            sv.w = (mq && mk_s[dg4 + 3]) ? sc[i][3] * 0.125f : -1e30f;
            *(float4*)&s_s[rg4 + i][dg4] = sv;
        }
        __syncthreads();

        float pm = -INFINITY;
#pragma unroll
        for (int c = 0; c < 16; c += 4) {
            float4 v4 = *(float4*)&s_s[rr][q4 * 16 + c];
            pm = fmaxf(pm, fmaxf(fmaxf(v4.x, v4.y), fmaxf(v4.z, v4.w)));
        }
        red_max[rr][q4] = pm;
        __syncthreads();

        float mo = row_m[rr];
        float mn = fmaxf(fmaxf(fmaxf(red_max[rr][0], red_max[rr][1]),
                               fmaxf(red_max[rr][2], red_max[rr][3])), mo);
        float ls = 0.0f;
#pragma unroll
        for (int c = 0; c < 16; c += 4) {
            float4 v4 = *(float4*)&s_s[rr][q4 * 16 + c];
            v4.x = expf(v4.x - mn); v4.y = expf(v4.y - mn);
            v4.z = expf(v4.z - mn); v4.w = expf(v4.w - mn);
            ls += v4.x + v4.y + v4.z + v4.w;
            *(float4*)&s_s[rr][q4 * 16 + c] = v4;
        }
        red_sum[rr][q4] = ls;
        __syncthreads();

        if (q4 == 0) {
            float alpha = expf(mo - mn);
            row_alpha[rr] = alpha;
            row_l[rr] = row_l[rr] * alpha +
                        (red_sum[rr][0] + red_sum[rr][1] + red_sum[rr][2] + red_sum[rr][3]);
            row_m[rr] = mn;
        }
        __syncthreads();

        float al[4];
#pragma unroll
        for (int i = 0; i < 4; ++i) al[i] = row_alpha[rg4 + i];
#pragma unroll
        for (int i = 0; i < 4; ++i)
#pragma unroll
            for (int j = 0; j < 4; ++j) o[i][j] *= al[i];

        for (int c0 = 0; c0 < 64; c0 += 4) {
            float pv[4][4], vw[4][4];
#pragma unroll
            for (int i = 0; i < 4; ++i) {
                float4 p = *(float4*)&s_s[rg4 + i][c0];
                pv[i][0] = p.x; pv[i][1] = p.y; pv[i][2] = p.z; pv[i][3] = p.w;
            }
#pragma unroll
            for (int c = 0; c < 4; ++c) {
                float4 u = *(float4*)&v_s[c0 + c][dg4];
                vw[c][0] = u.x; vw[c][1] = u.y; vw[c][2] = u.z; vw[c][3] = u.w;
            }
#pragma unroll
            for (int i = 0; i < 4; ++i)
#pragma unroll
                for (int c = 0; c < 4; ++c)
#pragma unroll
                    for (int j = 0; j < 4; ++j) o[i][j] += pv[i][c] * vw[c][j];
        }
        __syncthreads();
    }

#pragma unroll
    for (int i = 0; i < 4; ++i) {
        int row = rg4 + i;
        float inv = 1.0f / row_l[row];
        int ob = (s0 + row) * 1024 + h * 64 + dg4;
        *(float4*)&out[ob] = make_float4(o[i][0] * inv, o[i][1] * inv,
                                         o[i][2] * inv, o[i][3] * inv);
    }
}

extern "C" void kernel_launch(void* const* d_in, const int* in_sizes, int n_in,
                              void* d_out, int out_size, void* d_ws, size_t ws_size,
                              hipStream_t stream) {
    const float* query = (const float*)d_in[0];
    const float* key   = (const float*)d_in[1];
    const float* value = (const float*)d_in[2];
    const float* b_emb = (const float*)d_in[3];
    const void*  mask  = d_in[4];
    const float* ll    = (const float*)d_in[5];
    const float* bproj = (const float*)d_in[6];
    float* out = (float*)d_out;   // fp32 output — inputs are fp32, single-precision-mode harness

    const size_t HSD = (size_t)NHEAD * S_LEN * 64;   // 2M elements
    int* flags = (int*)d_ws;
    float* qr = (float*)((char*)d_ws + 4096);
    float* kr = qr + HSD;
    float* vr = kr + HSD;   // total ~24 MB + 4 KB

    dim3 pb(256), pg(16, 32);
    detect_kernel<<<1, 64, 0, stream>>>(mask, flags);
    proj_kernel<<<pg, pb, 0, stream>>>(query, b_emb, ll, bproj, qr, 0 * 1048576, 1);
    proj_kernel<<<pg, pb, 0, stream>>>(key,   b_emb, ll, bproj, kr, 1 * 1048576, 1);
    proj_kernel<<<pg, pb, 0, stream>>>(value, b_emb, ll, bproj, vr, 2 * 1048576, 0);
    attn_kernel<<<dim3(32, 16), pb, 0, stream>>>(qr, kr, vr, mask, out, flags);
}

// Round 7
// 744.985 us; speedup vs baseline: 3.3274x; 3.3274x over previous
//
#include <hip/hip_runtime.h>
#include <hip/hip_bf16.h>
#include <math.h>

#define S_LEN 2048
#define NHEAD 16
#define DMODEL 1024

__device__ __forceinline__ int mask_at(const void* mp, int enc, int s) {
    if (enc) return ((const unsigned char*)mp)[s] != 0;
    return ((const unsigned int*)mp)[s] != 0u;
}

// flags[0]: 1 if mask is byte-encoded bools, 0 if word-encoded (int32/float32)
__global__ void detect_kernel(const void* __restrict__ mask, int* __restrict__ flags) {
    if (threadIdx.x == 0 && blockIdx.x == 0) {
        const unsigned int* m = (const unsigned int*)mask;
        int bytey = 0;
        for (int i = 0; i < 8; ++i) {
            unsigned int u = m[i];
            if (u != 0u && u != 1u && u != 0x3F800000u) bytey = 1;
        }
        flags[0] = bytey;
    }
}

// x-projection (+optional fused b_rotate GEMM & RoPE). Writes fp32 [h][s][d].
__global__ __launch_bounds__(256)
void proj_kernel(const float* __restrict__ X, const float* __restrict__ b_emb,
                 const float* __restrict__ ll, const float* __restrict__ bproj,
                 float* __restrict__ outf, int woff, int dorope) {
    __shared__ float Ax[16][68], Ab[16][68], Wx[16][68], Wb[16][68];
    const int t = threadIdx.x;
    const int head = blockIdx.x;
    const int s0 = blockIdx.y * 64;
    const int tx = t & 15, ty = t >> 4;
    const int arow = t >> 2, akg = (t & 3) * 4;
    const int wrow = t >> 4, wng = (t & 15) * 4;

    float acc[4][4] = {}, accb[4][4] = {};
    for (int k0 = 0; k0 < DMODEL; k0 += 16) {
        float4 av = *(const float4*)&X[(s0 + arow) * DMODEL + k0 + akg];
        float4 wv = *(const float4*)&ll[woff + (k0 + wrow) * DMODEL + head * 64 + wng];
        Ax[akg + 0][arow] = av.x; Ax[akg + 1][arow] = av.y;
        Ax[akg + 2][arow] = av.z; Ax[akg + 3][arow] = av.w;
        *(float4*)&Wx[wrow][wng] = wv;
        if (dorope) {
            float4 bv = *(const float4*)&b_emb[(s0 + arow) * DMODEL + k0 + akg];
            float4 pv = *(const float4*)&bproj[(k0 + wrow) * DMODEL + head * 64 + wng];
            Ab[akg + 0][arow] = bv.x; Ab[akg + 1][arow] = bv.y;
            Ab[akg + 2][arow] = bv.z; Ab[akg + 3][arow] = bv.w;
            *(float4*)&Wb[wrow][wng] = pv;
        }
        __syncthreads();
#pragma unroll
        for (int kk = 0; kk < 16; ++kk) {
            float4 a = *(float4*)&Ax[kk][ty * 4];
            float4 wa = *(float4*)&Wx[kk][tx * 4];
            float af[4] = {a.x, a.y, a.z, a.w};
            float wf[4] = {wa.x, wa.y, wa.z, wa.w};
#pragma unroll
            for (int i = 0; i < 4; ++i)
#pragma unroll
                for (int j = 0; j < 4; ++j) acc[i][j] += af[i] * wf[j];
            if (dorope) {
                float4 b = *(float4*)&Ab[kk][ty * 4];
                float4 wb = *(float4*)&Wb[kk][tx * 4];
                float bf[4] = {b.x, b.y, b.z, b.w};
                float pf[4] = {wb.x, wb.y, wb.z, wb.w};
#pragma unroll
                for (int i = 0; i < 4; ++i)
#pragma unroll
                    for (int j = 0; j < 4; ++j) accb[i][j] += bf[i] * pf[j];
            }
        }
        __syncthreads();
    }

    if (dorope) {
        double inv0 = pow(10000.0, -(double)(2 * tx) / 32.0);
        double inv1 = pow(10000.0, -(double)(2 * tx + 1) / 32.0);
#pragma unroll
        for (int i = 0; i < 4; ++i) {
            int sr = s0 + ty * 4 + i;
            double a0 = (double)sr * inv0, a1 = (double)sr * inv1;
            float sn0 = (float)sin(a0), cs0 = (float)cos(a0);
            float sn1 = (float)sin(a1), cs1 = (float)cos(a1);
            float e0 = acc[i][0] * cs0 - acc[i][1] * sn0;
            float o0 = acc[i][0] * sn0 + acc[i][1] * cs0;
            float e1 = acc[i][2] * cs1 - acc[i][3] * sn1;
            float o1 = acc[i][2] * sn1 + acc[i][3] * cs1;
            int base = (head * S_LEN + sr) * 64 + tx * 4;
            *(float4*)&outf[base] = make_float4(e0 * accb[i][0], o0 * accb[i][1],
                                                e1 * accb[i][2], o1 * accb[i][3]);
        }
    } else {
#pragma unroll
        for (int i = 0; i < 4; ++i) {
            int sr = s0 + ty * 4 + i;
            *(float4*)&outf[(head * S_LEN + sr) * 64 + tx * 4] =
                make_float4(acc[i][0], acc[i][1], acc[i][2], acc[i][3]);
        }
    }
}

// Flash attention v2: transposed-K LDS, register softmax state + shfl reductions,
// 3 barriers/tile, register prefetch of next K/V tile. out fp32 [s][h*64+d].
__global__ __launch_bounds__(256)
void attn_kernel(const float* __restrict__ qr, const float* __restrict__ kr,
                 const float* __restrict__ vr, const void* __restrict__ mask,
                 float* __restrict__ out, const int* __restrict__ flags) {
    __shared__ float q_s[64][68];    // q_s[row][d]
    __shared__ float kt_s[64][68];   // kt_s[d][key]  (transposed!)
    __shared__ float v_s[64][68];    // v_s[key][d]
    __shared__ float p_s[64][68];    // p_s[row][key]

    const int menc = flags[0];
    const int t = threadIdx.x;
    const int h = blockIdx.y;
    const int s0 = blockIdx.x * 64;
    const int tx = t & 15;          // key-group (QK) / dim-group (PV)
    const int ty = t >> 4;          // row-group
    const int rg4 = ty * 4;
    const int cg4 = tx * 4;

    // load q tile (row-major, coalesced)
    const float* qbase = qr + (h * S_LEN + s0) * 64;
#pragma unroll
    for (int it = 0; it < 4; ++it) {
        int id = it * 256 + t;
        int row = id >> 4, c4 = (id & 15) * 4;
        *(float4*)&q_s[row][c4] = *(const float4*)&qbase[row * 64 + c4];
    }

    float m_i[4], l_i[4], o[4][4] = {};
#pragma unroll
    for (int i = 0; i < 4; ++i) { m_i[i] = -INFINITY; l_i[i] = 0.0f; }
    int mq[4];
#pragma unroll
    for (int i = 0; i < 4; ++i) mq[i] = mask_at(mask, menc, s0 + rg4 + i);

    const float* kb_h = kr + h * S_LEN * 64;
    const float* vb_h = vr + h * S_LEN * 64;

    // prefetch tile 0 into registers
    float4 kreg[4], vreg[4];
#pragma unroll
    for (int it = 0; it < 4; ++it) {
        int id = it * 256 + t;
        int row = id >> 4, c4 = (id & 15) * 4;
        kreg[it] = *(const float4*)&kb_h[row * 64 + c4];
        vreg[it] = *(const float4*)&vb_h[row * 64 + c4];
    }
    __syncthreads();   // q_s visible before first QK

    for (int kt = 0; kt < 32; ++kt) {
        // commit prefetched K (transposed) and V (row-major) to LDS
#pragma unroll
        for (int it = 0; it < 4; ++it) {
            int id = it * 256 + t;
            int row = id >> 4, c4 = (id & 15) * 4;
            kt_s[c4 + 0][row] = kreg[it].x;
            kt_s[c4 + 1][row] = kreg[it].y;
            kt_s[c4 + 2][row] = kreg[it].z;
            kt_s[c4 + 3][row] = kreg[it].w;
            *(float4*)&v_s[row][c4] = vreg[it];
        }
        int mk[4];
#pragma unroll
        for (int j = 0; j < 4; ++j) mk[j] = mask_at(mask, menc, kt * 64 + cg4 + j);
        __syncthreads();   // barrier 1: tiles staged

        // prefetch next tile while computing
        if (kt + 1 < 32) {
            const int kb = (kt + 1) * 64;
#pragma unroll
            for (int it = 0; it < 4; ++it) {
                int id = it * 256 + t;
                int row = id >> 4, c4 = (id & 15) * 4;
                kreg[it] = *(const float4*)&kb_h[(kb + row) * 64 + c4];
                vreg[it] = *(const float4*)&vb_h[(kb + row) * 64 + c4];
            }
        }

        // ---- QK^T: sc[i][j], rows rg4+i, keys cg4+j ----
        float sc[4][4] = {};
#pragma unroll 2
        for (int d0 = 0; d0 < 64; d0 += 4) {
            float4 qa[4], kk[4];
#pragma unroll
            for (int i = 0; i < 4; ++i) qa[i] = *(float4*)&q_s[rg4 + i][d0];
#pragma unroll
            for (int m = 0; m < 4; ++m) kk[m] = *(float4*)&kt_s[d0 + m][cg4];
#pragma unroll
            for (int i = 0; i < 4; ++i) {
                float qf[4] = {qa[i].x, qa[i].y, qa[i].z, qa[i].w};
#pragma unroll
                for (int m = 0; m < 4; ++m) {
                    sc[i][0] += qf[m] * kk[m].x;
                    sc[i][1] += qf[m] * kk[m].y;
                    sc[i][2] += qf[m] * kk[m].z;
                    sc[i][3] += qf[m] * kk[m].w;
                }
            }
        }

        // ---- mask + scale ----
        float sm[4][4];
#pragma unroll
        for (int i = 0; i < 4; ++i)
#pragma unroll
            for (int j = 0; j < 4; ++j)
                sm[i][j] = (mq[i] && mk[j]) ? sc[i][j] * 0.125f : -1e30f;

        // ---- row max via shfl over the 16 lanes sharing a row-group ----
        float rmax[4];
#pragma unroll
        for (int i = 0; i < 4; ++i)
            rmax[i] = fmaxf(fmaxf(sm[i][0], sm[i][1]), fmaxf(sm[i][2], sm[i][3]));
#pragma unroll
        for (int off = 1; off <= 8; off <<= 1)
#pragma unroll
            for (int i = 0; i < 4; ++i)
                rmax[i] = fmaxf(rmax[i], __shfl_xor(rmax[i], off, 64));

        float mn[4], alpha[4];
#pragma unroll
        for (int i = 0; i < 4; ++i) {
            mn[i] = fmaxf(m_i[i], rmax[i]);
            alpha[i] = __expf(m_i[i] - mn[i]);
            m_i[i] = mn[i];
        }

        // ---- exp, row sums, P to LDS ----
        float rsum[4];
#pragma unroll
        for (int i = 0; i < 4; ++i) {
            float e0 = __expf(sm[i][0] - mn[i]);
            float e1 = __expf(sm[i][1] - mn[i]);
            float e2 = __expf(sm[i][2] - mn[i]);
            float e3 = __expf(sm[i][3] - mn[i]);
            p_s[rg4 + i][cg4 + 0] = e0;
            p_s[rg4 + i][cg4 + 1] = e1;
            p_s[rg4 + i][cg4 + 2] = e2;
            p_s[rg4 + i][cg4 + 3] = e3;
            rsum[i] = e0 + e1 + e2 + e3;
        }
#pragma unroll
        for (int off = 1; off <= 8; off <<= 1)
#pragma unroll
            for (int i = 0; i < 4; ++i)
                rsum[i] += __shfl_xor(rsum[i], off, 64);
#pragma unroll
        for (int i = 0; i < 4; ++i) l_i[i] = l_i[i] * alpha[i] + rsum[i];

        // rescale running output
#pragma unroll
        for (int i = 0; i < 4; ++i)
#pragma unroll
            for (int c = 0; c < 4; ++c) o[i][c] *= alpha[i];

        __syncthreads();   // barrier 2: P visible

        // ---- PV: o[i][c], rows rg4+i, dims cg4+c ----
#pragma unroll 2
        for (int c0 = 0; c0 < 64; c0 += 4) {
            float4 pv[4], vv[4];
#pragma unroll
            for (int i = 0; i < 4; ++i) pv[i] = *(float4*)&p_s[rg4 + i][c0];
#pragma unroll
            for (int cc = 0; cc < 4; ++cc) vv[cc] = *(float4*)&v_s[c0 + cc][cg4];
#pragma unroll
            for (int i = 0; i < 4; ++i) {
                float pf[4] = {pv[i].x, pv[i].y, pv[i].z, pv[i].w};
#pragma unroll
                for (int cc = 0; cc < 4; ++cc) {
                    o[i][0] += pf[cc] * vv[cc].x;
                    o[i][1] += pf[cc] * vv[cc].y;
                    o[i][2] += pf[cc] * vv[cc].z;
                    o[i][3] += pf[cc] * vv[cc].w;
                }
            }
        }
        __syncthreads();   // barrier 3: safe to overwrite kt_s/v_s/p_s
    }

#pragma unroll
    for (int i = 0; i < 4; ++i) {
        float inv = 1.0f / l_i[i];
        int ob = (s0 + rg4 + i) * 1024 + h * 64 + cg4;
        *(float4*)&out[ob] = make_float4(o[i][0] * inv, o[i][1] * inv,
                                         o[i][2] * inv, o[i][3] * inv);
    }
}

extern "C" void kernel_launch(void* const* d_in, const int* in_sizes, int n_in,
                              void* d_out, int out_size, void* d_ws, size_t ws_size,
                              hipStream_t stream) {
    const float* query = (const float*)d_in[0];
    const float* key   = (const float*)d_in[1];
    const float* value = (const float*)d_in[2];
    const float* b_emb = (const float*)d_in[3];
    const void*  mask  = d_in[4];
    const float* ll    = (const float*)d_in[5];
    const float* bproj = (const float*)d_in[6];
    float* out = (float*)d_out;

    const size_t HSD = (size_t)NHEAD * S_LEN * 64;   // 2M elements
    int* flags = (int*)d_ws;
    float* qr = (float*)((char*)d_ws + 4096);
    float* kr = qr + HSD;
    float* vr = kr + HSD;   // total ~24 MB + 4 KB

    dim3 pb(256), pg(16, 32);
    detect_kernel<<<1, 64, 0, stream>>>(mask, flags);
    proj_kernel<<<pg, pb, 0, stream>>>(query, b_emb, ll, bproj, qr, 0 * 1048576, 1);
    proj_kernel<<<pg, pb, 0, stream>>>(key,   b_emb, ll, bproj, kr, 1 * 1048576, 1);
    proj_kernel<<<pg, pb, 0, stream>>>(value, b_emb, ll, bproj, vr, 2 * 1048576, 0);
    attn_kernel<<<dim3(32, 16), pb, 0, stream>>>(qr, kr, vr, mask, out, flags);
}

// Round 8
// 626.439 us; speedup vs baseline: 3.9571x; 1.1892x over previous
//
#include <hip/hip_runtime.h>
#include <hip/hip_bf16.h>
#include <math.h>

#define S_LEN 2048
#define NHEAD 16
#define DMODEL 1024

typedef short bf16x8 __attribute__((ext_vector_type(8)));
typedef float f32x4 __attribute__((ext_vector_type(4)));

__device__ __forceinline__ int mask_at(const void* mp, int enc, int s) {
    if (enc) return ((const unsigned char*)mp)[s] != 0;
    return ((const unsigned int*)mp)[s] != 0u;
}

// flags[0]: 1 if mask is byte-encoded bools, 0 if word-encoded (int32/float32)
__global__ void detect_kernel(const void* __restrict__ mask, int* __restrict__ flags) {
    if (threadIdx.x == 0 && blockIdx.x == 0) {
        const unsigned int* m = (const unsigned int*)mask;
        int bytey = 0;
        for (int i = 0; i < 8; ++i) {
            unsigned int u = m[i];
            if (u != 0u && u != 1u && u != 0x3F800000u) bytey = 1;
        }
        flags[0] = bytey;
    }
}

// split fp32 -> bf16 hi + bf16 lo (truncation; combined rep error ~2^-16 rel)
__device__ __forceinline__ void split8(const float* v, bf16x8& hi, bf16x8& lo) {
#pragma unroll
    for (int j = 0; j < 8; ++j) {
        unsigned int u = __float_as_uint(v[j]);
        unsigned int bh = u & 0xFFFF0000u;
        float l = v[j] - __uint_as_float(bh);
        hi[j] = (short)(bh >> 16);
        lo[j] = (short)(__float_as_uint(l) >> 16);
    }
}

// MFMA split-bf16 projection (+optional fused b_rotate GEMM & lane-local RoPE).
// Computes C^T: A := W^T fragments, B := X^T fragments, so C row=head-dim, col=s.
// Writes fp32 [h][s][d]. grid (16 heads, 32 s-tiles), 256 threads (4 waves = 4 d-tiles).
__global__ __launch_bounds__(256)
void proj_mfma(const float* __restrict__ X, const float* __restrict__ b_emb,
               const float* __restrict__ ll, const float* __restrict__ bproj,
               float* __restrict__ outf, int woff, int dorope) {
    __shared__ __align__(16) float Xs[64][36];   // X^T source: Xs[s][k]
    __shared__ __align__(16) float Bs[64][36];   // b_emb tile
    __shared__ __align__(16) float Ws[32][68];   // W tile: Ws[k][n]
    __shared__ __align__(16) float Ps[32][68];   // bproj tile

    const int t = threadIdx.x;
    const int h = blockIdx.x;
    const int s0 = blockIdx.y * 64;
    const int lane = t & 63;
    const int dt = t >> 6;        // wave = d-tile (16 head-dims)
    const int quad = lane >> 4;
    const int c = lane & 15;

    f32x4 accx[4] = {{0.f,0.f,0.f,0.f},{0.f,0.f,0.f,0.f},{0.f,0.f,0.f,0.f},{0.f,0.f,0.f,0.f}};
    f32x4 accb[4] = {{0.f,0.f,0.f,0.f},{0.f,0.f,0.f,0.f},{0.f,0.f,0.f,0.f},{0.f,0.f,0.f,0.f}};

    for (int k0 = 0; k0 < DMODEL; k0 += 32) {
        __syncthreads();   // previous chunk's LDS readers done
#pragma unroll
        for (int i = 0; i < 2; ++i) {
            int id = i * 256 + t;
            int row = id >> 3, k4 = (id & 7) * 4;
            *(float4*)&Xs[row][k4] = *(const float4*)&X[(s0 + row) * DMODEL + k0 + k4];
            if (dorope)
                *(float4*)&Bs[row][k4] = *(const float4*)&b_emb[(s0 + row) * DMODEL + k0 + k4];
        }
#pragma unroll
        for (int i = 0; i < 2; ++i) {
            int id = i * 256 + t;
            int r = id >> 4, n4 = (id & 15) * 4;
            *(float4*)&Ws[r][n4] = *(const float4*)&ll[woff + (k0 + r) * DMODEL + h * 64 + n4];
            if (dorope)
                *(float4*)&Ps[r][n4] = *(const float4*)&bproj[(k0 + r) * DMODEL + h * 64 + n4];
        }
        __syncthreads();

        // A-frags (W^T): element j = W[k0 + quad*8 + j][h*64 + dt*16 + c]
        float av[8];
#pragma unroll
        for (int j = 0; j < 8; ++j) av[j] = Ws[quad * 8 + j][dt * 16 + c];
        bf16x8 Ahx, Alx; split8(av, Ahx, Alx);
        bf16x8 Ahb, Alb;
        if (dorope) {
#pragma unroll
            for (int j = 0; j < 8; ++j) av[j] = Ps[quad * 8 + j][dt * 16 + c];
            split8(av, Ahb, Alb);
        }

#pragma unroll
        for (int st = 0; st < 4; ++st) {
            // B-frag (X^T): element j = X[s0 + st*16 + c][k0 + quad*8 + j]
            float bv[8];
            float4 x0 = *(float4*)&Xs[st * 16 + c][quad * 8];
            float4 x1 = *(float4*)&Xs[st * 16 + c][quad * 8 + 4];
            bv[0]=x0.x; bv[1]=x0.y; bv[2]=x0.z; bv[3]=x0.w;
            bv[4]=x1.x; bv[5]=x1.y; bv[6]=x1.z; bv[7]=x1.w;
            bf16x8 Bh, Bl; split8(bv, Bh, Bl);
            accx[st] = __builtin_amdgcn_mfma_f32_16x16x32_bf16(Ahx, Bh, accx[st], 0, 0, 0);
            accx[st] = __builtin_amdgcn_mfma_f32_16x16x32_bf16(Ahx, Bl, accx[st], 0, 0, 0);
            accx[st] = __builtin_amdgcn_mfma_f32_16x16x32_bf16(Alx, Bh, accx[st], 0, 0, 0);
            if (dorope) {
                float4 b0 = *(float4*)&Bs[st * 16 + c][quad * 8];
                float4 b1 = *(float4*)&Bs[st * 16 + c][quad * 8 + 4];
                bv[0]=b0.x; bv[1]=b0.y; bv[2]=b0.z; bv[3]=b0.w;
                bv[4]=b1.x; bv[5]=b1.y; bv[6]=b1.z; bv[7]=b1.w;
                bf16x8 Bhb, Blb; split8(bv, Bhb, Blb);
                accb[st] = __builtin_amdgcn_mfma_f32_16x16x32_bf16(Ahb, Bhb, accb[st], 0, 0, 0);
                accb[st] = __builtin_amdgcn_mfma_f32_16x16x32_bf16(Ahb, Blb, accb[st], 0, 0, 0);
                accb[st] = __builtin_amdgcn_mfma_f32_16x16x32_bf16(Alb, Bhb, accb[st], 0, 0, 0);
            }
        }
    }

    // C/D layout: col=lane&15 (s), row=quad*4+reg (head-dim) -> lane holds 4 consecutive dims
    if (dorope) {
        int p0 = dt * 8 + 2 * quad;           // RoPE pair index of dims (4quad, 4quad+1)
        double inv0 = pow(10000.0, -(double)p0 / 32.0);
        double inv1 = pow(10000.0, -(double)(p0 + 1) / 32.0);
#pragma unroll
        for (int st = 0; st < 4; ++st) {
            int s = s0 + st * 16 + c;
            double a0 = (double)s * inv0, a1 = (double)s * inv1;
            float sn0 = (float)sin(a0), cs0 = (float)cos(a0);
            float sn1 = (float)sin(a1), cs1 = (float)cos(a1);
            float x0 = accx[st][0], x1 = accx[st][1];
            float x2 = accx[st][2], x3 = accx[st][3];
            float e0 = x0 * cs0 - x1 * sn0;
            float o0 = x0 * sn0 + x1 * cs0;
            float e1 = x2 * cs1 - x3 * sn1;
            float o1 = x2 * sn1 + x3 * cs1;
            int base = (h * S_LEN + s) * 64 + dt * 16 + 4 * quad;
            *(float4*)&outf[base] = make_float4(e0 * accb[st][0], o0 * accb[st][1],
                                                e1 * accb[st][2], o1 * accb[st][3]);
        }
    } else {
#pragma unroll
        for (int st = 0; st < 4; ++st) {
            int s = s0 + st * 16 + c;
            int base = (h * S_LEN + s) * 64 + dt * 16 + 4 * quad;
            *(float4*)&outf[base] = make_float4(accx[st][0], accx[st][1],
                                                accx[st][2], accx[st][3]);
        }
    }
}

// Flash attention v2 (unchanged from round 7): transposed-K LDS, register softmax,
// 3 barriers/tile, register prefetch. out fp32 [s][h*64+d].
__global__ __launch_bounds__(256)
void attn_kernel(const float* __restrict__ qr, const float* __restrict__ kr,
                 const float* __restrict__ vr, const void* __restrict__ mask,
                 float* __restrict__ out, const int* __restrict__ flags) {
    __shared__ float q_s[64][68];
    __shared__ float kt_s[64][68];
    __shared__ float v_s[64][68];
    __shared__ float p_s[64][68];

    const int menc = flags[0];
    const int t = threadIdx.x;
    const int h = blockIdx.y;
    const int s0 = blockIdx.x * 64;
    const int tx = t & 15;
    const int ty = t >> 4;
    const int rg4 = ty * 4;
    const int cg4 = tx * 4;

    const float* qbase = qr + (h * S_LEN + s0) * 64;
#pragma unroll
    for (int it = 0; it < 4; ++it) {
        int id = it * 256 + t;
        int row = id >> 4, c4 = (id & 15) * 4;
        *(float4*)&q_s[row][c4] = *(const float4*)&qbase[row * 64 + c4];
    }

    float m_i[4], l_i[4], o[4][4] = {};
#pragma unroll
    for (int i = 0; i < 4; ++i) { m_i[i] = -INFINITY; l_i[i] = 0.0f; }
    int mq[4];
#pragma unroll
    for (int i = 0; i < 4; ++i) mq[i] = mask_at(mask, menc, s0 + rg4 + i);

    const float* kb_h = kr + h * S_LEN * 64;
    const float* vb_h = vr + h * S_LEN * 64;

    float4 kreg[4], vreg[4];
#pragma unroll
    for (int it = 0; it < 4; ++it) {
        int id = it * 256 + t;
        int row = id >> 4, c4 = (id & 15) * 4;
        kreg[it] = *(const float4*)&kb_h[row * 64 + c4];
        vreg[it] = *(const float4*)&vb_h[row * 64 + c4];
    }
    __syncthreads();

    for (int kt = 0; kt < 32; ++kt) {
#pragma unroll
        for (int it = 0; it < 4; ++it) {
            int id = it * 256 + t;
            int row = id >> 4, c4 = (id & 15) * 4;
            kt_s[c4 + 0][row] = kreg[it].x;
            kt_s[c4 + 1][row] = kreg[it].y;
            kt_s[c4 + 2][row] = kreg[it].z;
            kt_s[c4 + 3][row] = kreg[it].w;
            *(float4*)&v_s[row][c4] = vreg[it];
        }
        int mk[4];
#pragma unroll
        for (int j = 0; j < 4; ++j) mk[j] = mask_at(mask, menc, kt * 64 + cg4 + j);
        __syncthreads();

        if (kt + 1 < 32) {
            const int kb = (kt + 1) * 64;
#pragma unroll
            for (int it = 0; it < 4; ++it) {
                int id = it * 256 + t;
                int row = id >> 4, c4 = (id & 15) * 4;
                kreg[it] = *(const float4*)&kb_h[(kb + row) * 64 + c4];
                vreg[it] = *(const float4*)&vb_h[(kb + row) * 64 + c4];
            }
        }

        float sc[4][4] = {};
#pragma unroll 2
        for (int d0 = 0; d0 < 64; d0 += 4) {
            float4 qa[4], kk[4];
#pragma unroll
            for (int i = 0; i < 4; ++i) qa[i] = *(float4*)&q_s[rg4 + i][d0];
#pragma unroll
            for (int m = 0; m < 4; ++m) kk[m] = *(float4*)&kt_s[d0 + m][cg4];
#pragma unroll
            for (int i = 0; i < 4; ++i) {
                float qf[4] = {qa[i].x, qa[i].y, qa[i].z, qa[i].w};
#pragma unroll
                for (int m = 0; m < 4; ++m) {
                    sc[i][0] += qf[m] * kk[m].x;
                    sc[i][1] += qf[m] * kk[m].y;
                    sc[i][2] += qf[m] * kk[m].z;
                    sc[i][3] += qf[m] * kk[m].w;
                }
            }
        }

        float sm[4][4];
#pragma unroll
        for (int i = 0; i < 4; ++i)
#pragma unroll
            for (int j = 0; j < 4; ++j)
                sm[i][j] = (mq[i] && mk[j]) ? sc[i][j] * 0.125f : -1e30f;

        float rmax[4];
#pragma unroll
        for (int i = 0; i < 4; ++i)
            rmax[i] = fmaxf(fmaxf(sm[i][0], sm[i][1]), fmaxf(sm[i][2], sm[i][3]));
#pragma unroll
        for (int off = 1; off <= 8; off <<= 1)
#pragma unroll
            for (int i = 0; i < 4; ++i)
                rmax[i] = fmaxf(rmax[i], __shfl_xor(rmax[i], off, 64));

        float mn[4], alpha[4];
#pragma unroll
        for (int i = 0; i < 4; ++i) {
            mn[i] = fmaxf(m_i[i], rmax[i]);
            alpha[i] = __expf(m_i[i] - mn[i]);
            m_i[i] = mn[i];
        }

        float rsum[4];
#pragma unroll
        for (int i = 0; i < 4; ++i) {
            float e0 = __expf(sm[i][0] - mn[i]);
            float e1 = __expf(sm[i][1] - mn[i]);
            float e2 = __expf(sm[i][2] - mn[i]);
            float e3 = __expf(sm[i][3] - mn[i]);
            p_s[rg4 + i][cg4 + 0] = e0;
            p_s[rg4 + i][cg4 + 1] = e1;
            p_s[rg4 + i][cg4 + 2] = e2;
            p_s[rg4 + i][cg4 + 3] = e3;
            rsum[i] = e0 + e1 + e2 + e3;
        }
#pragma unroll
        for (int off = 1; off <= 8; off <<= 1)
#pragma unroll
            for (int i = 0; i < 4; ++i)
                rsum[i] += __shfl_xor(rsum[i], off, 64);
#pragma unroll
        for (int i = 0; i < 4; ++i) l_i[i] = l_i[i] * alpha[i] + rsum[i];

#pragma unroll
        for (int i = 0; i < 4; ++i)
#pragma unroll
            for (int cQ = 0; cQ < 4; ++cQ) o[i][cQ] *= alpha[i];

        __syncthreads();

#pragma unroll 2
        for (int c0 = 0; c0 < 64; c0 += 4) {
            float4 pv[4], vv[4];
#pragma unroll
            for (int i = 0; i < 4; ++i) pv[i] = *(float4*)&p_s[rg4 + i][c0];
#pragma unroll
            for (int cc = 0; cc < 4; ++cc) vv[cc] = *(float4*)&v_s[c0 + cc][cg4];
#pragma unroll
            for (int i = 0; i < 4; ++i) {
                float pf[4] = {pv[i].x, pv[i].y, pv[i].z, pv[i].w};
#pragma unroll
                for (int cc = 0; cc < 4; ++cc) {
                    o[i][0] += pf[cc] * vv[cc].x;
                    o[i][1] += pf[cc] * vv[cc].y;
                    o[i][2] += pf[cc] * vv[cc].z;
                    o[i][3] += pf[cc] * vv[cc].w;
                }
            }
        }
        __syncthreads();
    }

#pragma unroll
    for (int i = 0; i < 4; ++i) {
        float inv = 1.0f / l_i[i];
        int ob = (s0 + rg4 + i) * 1024 + h * 64 + cg4;
        *(float4*)&out[ob] = make_float4(o[i][0] * inv, o[i][1] * inv,
                                         o[i][2] * inv, o[i][3] * inv);
    }
}

extern "C" void kernel_launch(void* const* d_in, const int* in_sizes, int n_in,
                              void* d_out, int out_size, void* d_ws, size_t ws_size,
                              hipStream_t stream) {
    const float* query = (const float*)d_in[0];
    const float* key   = (const float*)d_in[1];
    const float* value = (const float*)d_in[2];
    const float* b_emb = (const float*)d_in[3];
    const void*  mask  = d_in[4];
    const float* ll    = (const float*)d_in[5];
    const float* bproj = (const float*)d_in[6];
    float* out = (float*)d_out;

    const size_t HSD = (size_t)NHEAD * S_LEN * 64;   // 2M elements
    int* flags = (int*)d_ws;
    float* qr = (float*)((char*)d_ws + 4096);
    float* kr = qr + HSD;
    float* vr = kr + HSD;   // total ~24 MB + 4 KB

    dim3 pb(256), pg(16, 32);
    detect_kernel<<<1, 64, 0, stream>>>(mask, flags);
    proj_mfma<<<pg, pb, 0, stream>>>(query, b_emb, ll, bproj, qr, 0 * 1048576, 1);
    proj_mfma<<<pg, pb, 0, stream>>>(key,   b_emb, ll, bproj, kr, 1 * 1048576, 1);
    proj_mfma<<<pg, pb, 0, stream>>>(value, b_emb, ll, bproj, vr, 2 * 1048576, 0);
    attn_kernel<<<dim3(32, 16), pb, 0, stream>>>(qr, kr, vr, mask, out, flags);
}